// Round 7
// baseline (21153.233 us; speedup 1.0000x reference)
//
#include <hip/hip_runtime.h>

// Problem sizes
static constexpr int NB = 1024;   // batch
static constexpr int NS = 200;    // seq len
static constexpr int NH = 256;    // hidden == embed
static constexpr int NG4 = 1024;  // 4*H
static constexpr int NK2 = 512;   // E + H

#define NEG_INF (-__builtin_inff())
static constexpr float LOG2E = 1.4426950408889634f;
static constexpr float LN2   = 0.6931471805599453f;

// ---------------- workspace layout (float offsets) ----------------
static constexpr size_t OFF_EGS  = 0;                                   // fp8 [B][200][256] (s-major)
static constexpr size_t OFF_EPS  = OFF_EGS + (size_t)NB*NS*NH/4;        // fp8 [B][200][256]
static constexpr size_t OFF_EGT  = OFF_EPS + (size_t)NB*NS*NH/4;        // fp8 [B][256][256] (o-major, S padded)
static constexpr size_t OFF_EPT  = OFF_EGT + (size_t)NB*NH*256/4;       // fp8 [B][256][256]
static constexpr size_t OFF_WCT  = OFF_EPT + (size_t)NB*NH*256/4;       // WcatT reordered [512][1024]
static constexpr size_t OFF_BSUM = OFF_WCT + (size_t)NK2*NG4;           // [1024] b_ih+b_hh reordered
static constexpr size_t OFF_WQTG = OFF_BSUM + 1024;                     // [h][o]
static constexpr size_t OFF_WQTP = OFF_WQTG + (size_t)NH*NH;
static constexpr size_t OFF_WRTG = OFF_WQTP + (size_t)NH*NH;
static constexpr size_t OFF_WRTP = OFF_WRTG + (size_t)NH*NH;
static constexpr size_t OFF_H0   = OFF_WRTP + (size_t)NH*NH;            // h parity buffers
static constexpr size_t OFF_H1   = OFF_H0 + (size_t)NB*NH;
static constexpr size_t OFF_C    = OFF_H1 + (size_t)NB*NH;              // c (in-place)
static constexpr size_t OFF_DEC  = OFF_C + (size_t)NB*NH;               // dec_in [B][E]
static constexpr size_t OFF_QPG  = OFF_DEC + (size_t)NB*NH;             // [B][H]
static constexpr size_t OFF_GL   = OFF_QPG + (size_t)NB*NH;             // [B][H]
static constexpr size_t OFF_QPP  = OFF_GL + (size_t)NB*NH;              // [B][H]
static constexpr size_t OFF_MASK = OFF_QPP + (size_t)NB*NH;             // uint8 [B][S]

// ---------------- output layout (float offsets) ----------------
static constexpr size_t OUT_SELS = (size_t)NB*NS*NS;   // log_p first
static constexpr size_t OUT_H    = OUT_SELS + (size_t)NB*NS;
static constexpr size_t OUT_C    = OUT_H + (size_t)NB*NH;

// ---------------- fast math ----------------
typedef float f32x2 __attribute__((ext_vector_type(2)));

__device__ __forceinline__ float fast_exp2(float x) {
  float d; asm("v_exp_f32 %0, %1" : "=v"(d) : "v"(x)); return d;
}
__device__ __forceinline__ float fast_rcp(float x) {
  float d; asm("v_rcp_f32 %0, %1" : "=v"(d) : "v"(x)); return d;
}
__device__ __forceinline__ float fast_log2(float x) {
  float d; asm("v_log_f32 %0, %1" : "=v"(d) : "v"(x)); return d;
}
// tanh(x) = 1 - 2/(e^{2x}+1)
__device__ __forceinline__ float fast_tanh(float x) {
  float e = fast_exp2(x * (2.0f * LOG2E));
  return fmaf(-2.0f, fast_rcp(e + 1.0f), 1.0f);
}
__device__ __forceinline__ float fast_sigm(float x) {
  float e = fast_exp2(x * (-LOG2E));
  return fast_rcp(1.0f + e);
}
// exp(a) for a<=0 (a may be -inf -> 0)
__device__ __forceinline__ float fast_expn(float a) {
  return fast_exp2(a * LOG2E);
}
// HW decode: 2 OCP-e4m3 bytes (low 16 bits of u) -> 2 floats
__device__ __forceinline__ f32x2 cvt2_fp8(unsigned int u) {
  f32x2 d; asm("v_cvt_pk_f32_fp8 %0, %1" : "=v"(d) : "v"(u)); return d;
}
// software encode f32 -> OCP e4m3 (RNE, clamp +-448, flush tiny to 0)
__device__ __forceinline__ unsigned int f32_to_e4m3(float x) {
  x = fminf(fmaxf(x, -448.0f), 448.0f);
  unsigned int u = __float_as_uint(x);
  unsigned int s = (u >> 24) & 0x80u;
  unsigned int au = u & 0x7fffffffu;
  if (au < 0x3c800000u) return s;
  unsigned int r = au + 0x7ffffu + ((au >> 20) & 1u);
  unsigned int expf8 = (r >> 23) - 120u;
  unsigned int man = (r >> 20) & 7u;
  return s | (expf8 << 3) | man;
}

// ---------------- init ----------------
__global__ __launch_bounds__(256) void k_init(
    const float* __restrict__ dec0, const float* __restrict__ h0, const float* __restrict__ c0,
    const float* __restrict__ W_ih, const float* __restrict__ W_hh,
    const float* __restrict__ b_ih, const float* __restrict__ b_hh,
    const float* __restrict__ Wq_g, const float* __restrict__ Wq_p,
    const float* __restrict__ Wref_g, const float* __restrict__ Wref_p,
    float* __restrict__ ws)
{
  const int i0 = blockIdx.x * 256 + threadIdx.x;
  const int stride = gridDim.x * 256;
  float* WcatT = ws + OFF_WCT;
  float* BS   = ws + OFF_BSUM;
  float* WqTg = ws + OFF_WQTG;
  float* WqTp = ws + OFF_WQTP;
  float* WrTg = ws + OFF_WRTG;
  float* WrTp = ws + OFF_WRTP;
  // reordered: col j = h*4 + g  (gate-interleaved)
  for (int t = i0; t < NK2 * NG4; t += stride) {
    int k = t >> 10, j = t & 1023;
    int hcol = j >> 2, g = j & 3;
    int row = g * 256 + hcol;
    WcatT[t] = (k < NH) ? W_ih[row * NH + k] : W_hh[row * NH + (k - NH)];
  }
  for (int t = i0; t < 1024; t += stride) {
    int hcol = t >> 2, g = t & 3;
    BS[t] = b_ih[g * 256 + hcol] + b_hh[g * 256 + hcol];
  }
  for (int t = i0; t < NH * NH; t += stride) {
    int h = t >> 8, o = t & 255;
    WqTg[t] = Wq_g[o * NH + h];
    WqTp[t] = Wq_p[o * NH + h];
    WrTg[t] = Wref_g[o * NH + h];
    WrTp[t] = Wref_p[o * NH + h];
  }
  float* hbuf = ws + OFF_H0;
  float* cbuf = ws + OFF_C;
  float* dbuf = ws + OFF_DEC;
  for (int t = i0; t < NB * NH; t += stride) {
    hbuf[t] = h0[t]; cbuf[t] = c0[t]; dbuf[t] = dec0[t];
  }
  unsigned int* mask32 = (unsigned int*)(ws + OFF_MASK);
  for (int t = i0; t < NB * NS / 4; t += stride) mask32[t] = 0u;
}

// ---------------- e projection GEMM -> fp8 [B][S][O] ----------------
__global__ __launch_bounds__(256) void k_eproj(
    const float* __restrict__ A,    // context flat [S*B][256]
    const float* __restrict__ WT,   // [256][256]
    const float* __restrict__ bias,
    unsigned char* __restrict__ e)  // [B][200][256] fp8
{
  __shared__ float As[32][68];
  __shared__ float Bs[32][68];
  const int r0 = blockIdx.y * 64;
  const int n0 = blockIdx.x * 64;
  const int tid = threadIdx.x;
  const int tm = tid & 15, tn = tid >> 4;
  float acc[4][4] = {};
  for (int k0 = 0; k0 < 256; k0 += 32) {
    __syncthreads();
    {
      const int m = tid >> 2;
      const int kq = (tid & 3) * 8;
      const float* src = A + (size_t)(r0 + m) * 256 + k0 + kq;
      float4 v0 = *(const float4*)src;
      float4 v1 = *(const float4*)(src + 4);
      As[kq + 0][m] = v0.x; As[kq + 1][m] = v0.y; As[kq + 2][m] = v0.z; As[kq + 3][m] = v0.w;
      As[kq + 4][m] = v1.x; As[kq + 5][m] = v1.y; As[kq + 6][m] = v1.z; As[kq + 7][m] = v1.w;
    }
    {
      const int kb = tid >> 3;
      const int nq = (tid & 7) * 8;
      const float* src = WT + (size_t)(k0 + kb) * 256 + n0 + nq;
      *(float4*)&Bs[kb][nq] = *(const float4*)src;
      *(float4*)&Bs[kb][nq + 4] = *(const float4*)(src + 4);
    }
    __syncthreads();
#pragma unroll
    for (int k = 0; k < 32; ++k) {
      float4 a = *(const float4*)&As[k][tm * 4];
      float4 bq = *(const float4*)&Bs[k][tn * 4];
      float av[4] = {a.x, a.y, a.z, a.w};
      float bv[4] = {bq.x, bq.y, bq.z, bq.w};
#pragma unroll
      for (int i = 0; i < 4; ++i)
#pragma unroll
        for (int j = 0; j < 4; ++j) acc[i][j] += av[i] * bv[j];
    }
  }
  float4 bvv = *(const float4*)(bias + n0 + tn * 4);
  float bb[4] = {bvv.x, bvv.y, bvv.z, bvv.w};
#pragma unroll
  for (int i = 0; i < 4; ++i) {
    int R = r0 + tm * 4 + i;
    int b = R & 1023, s = R >> 10;
    unsigned int pk = f32_to_e4m3(acc[i][0] + bb[0])
                    | (f32_to_e4m3(acc[i][1] + bb[1]) << 8)
                    | (f32_to_e4m3(acc[i][2] + bb[2]) << 16)
                    | (f32_to_e4m3(acc[i][3] + bb[3]) << 24);
    *(unsigned int*)(e + (size_t)b * (NS * NH) + (size_t)s * NH + n0 + tn * 4) = pk;
  }
}

// ---------------- one-time transpose: [B][200][256] -> [B][256][256] (S padded, pad=0) ----
__global__ __launch_bounds__(256) void k_etr(
    const unsigned char* __restrict__ src, unsigned char* __restrict__ dst)
{
  __shared__ unsigned char tile[64][260];
  const int b = blockIdx.x;
  const int s0 = blockIdx.y * 64;
  const int tid = threadIdx.x;
#pragma unroll
  for (int j = 0; j < 16; ++j) {
    int idx = j * 256 + tid;
    int sl = idx >> 6;
    int c4 = (idx & 63) * 4;
    unsigned int v = 0;
    if (s0 + sl < NS)
      v = *(const unsigned int*)(src + (size_t)b * (NS * NH) + (size_t)(s0 + sl) * NH + c4);
    *(unsigned int*)&tile[sl][c4] = v;
  }
  __syncthreads();
#pragma unroll
  for (int j = 0; j < 16; ++j) {
    int idx = j * 256 + tid;
    int o = idx >> 4;
    int cd = (idx & 15) * 4;
    unsigned int v = (unsigned int)tile[cd + 0][o]
                   | ((unsigned int)tile[cd + 1][o] << 8)
                   | ((unsigned int)tile[cd + 2][o] << 16)
                   | ((unsigned int)tile[cd + 3][o] << 24);
    *(unsigned int*)(dst + (size_t)b * 65536 + (size_t)o * 256 + s0 + cd) = v;
  }
}

// ---------------- gates GEMM + fused LSTM activation (gate-interleaved W) ----------------
// col j = h*4+g; thread micro-tile = 1 h-col x 4 gates -> epilogue computes c,h directly.
__global__ __launch_bounds__(256) void k_gates_lstm(
    const float* __restrict__ dec_in, const float* __restrict__ h_in,
    const float* __restrict__ WcatT, const float* __restrict__ BS,
    float* __restrict__ c, float* __restrict__ h_out)
{
  __shared__ float As[32][34];
  __shared__ float Bs[32][68];
  const int r0 = blockIdx.y * 32;
  const int n0 = blockIdx.x * 64;
  const int tid = threadIdx.x;
  const int tm = tid & 15, tn = tid >> 4;
  float acc[2][4] = {};
  for (int k0 = 0; k0 < 512; k0 += 32) {
    __syncthreads();
    {
      const int m = tid >> 3;
      const int kq = (tid & 7) * 4;
      const int kk = k0 + kq;
      const float* src = (kk < 256) ? (dec_in + (size_t)(r0 + m) * 256 + kk)
                                    : (h_in + (size_t)(r0 + m) * 256 + (kk - 256));
      float4 v = *(const float4*)src;
      As[kq + 0][m] = v.x; As[kq + 1][m] = v.y; As[kq + 2][m] = v.z; As[kq + 3][m] = v.w;
    }
    {
      const int kb = tid >> 3;
      const int nq = (tid & 7) * 8;
      const float* src = WcatT + (size_t)(k0 + kb) * 1024 + n0 + nq;
      *(float4*)&Bs[kb][nq] = *(const float4*)src;
      *(float4*)&Bs[kb][nq + 4] = *(const float4*)(src + 4);
    }
    __syncthreads();
#pragma unroll
    for (int k = 0; k < 32; ++k) {
      float a0 = As[k][tm * 2 + 0], a1 = As[k][tm * 2 + 1];
      float4 bq = *(const float4*)&Bs[k][tn * 4];
      acc[0][0] += a0 * bq.x; acc[0][1] += a0 * bq.y; acc[0][2] += a0 * bq.z; acc[0][3] += a0 * bq.w;
      acc[1][0] += a1 * bq.x; acc[1][1] += a1 * bq.y; acc[1][2] += a1 * bq.z; acc[1][3] += a1 * bq.w;
    }
  }
  const int j0 = n0 + tn * 4;
  const int hc = (j0 >> 2);           // h column
  float b0 = BS[j0], b1 = BS[j0 + 1], b2 = BS[j0 + 2], b3 = BS[j0 + 3];
#pragma unroll
  for (int i = 0; i < 2; ++i) {
    int r = r0 + tm * 2 + i;
    float gi = acc[i][0] + b0;
    float gf = acc[i][1] + b1;
    float gg = acc[i][2] + b2;
    float go = acc[i][3] + b3;
    float cprev = c[(size_t)r * 256 + hc];
    float cn = fast_sigm(gf) * cprev + fast_sigm(gi) * fast_tanh(gg);
    c[(size_t)r * 256 + hc] = cn;
    h_out[(size_t)r * 256 + hc] = fast_sigm(go) * fast_tanh(cn);
  }
}

// ---------------- generic 1024x256 = (1024x256)x(256x256) GEMM + bias ----------------
__global__ __launch_bounds__(256) void k_mv256(
    const float* __restrict__ A, const float* __restrict__ WT,
    const float* __restrict__ bias, float* __restrict__ C)
{
  __shared__ float As[32][34];
  __shared__ float Bs[32][68];
  const int r0 = blockIdx.y * 32;
  const int n0 = blockIdx.x * 64;
  const int tid = threadIdx.x;
  const int tm = tid & 15, tn = tid >> 4;
  float acc[2][4] = {};
  for (int k0 = 0; k0 < 256; k0 += 32) {
    __syncthreads();
    {
      const int m = tid >> 3;
      const int kq = (tid & 7) * 4;
      const float* src = A + (size_t)(r0 + m) * 256 + k0 + kq;
      float4 v = *(const float4*)src;
      As[kq + 0][m] = v.x; As[kq + 1][m] = v.y; As[kq + 2][m] = v.z; As[kq + 3][m] = v.w;
    }
    {
      const int kb = tid >> 3;
      const int nq = (tid & 7) * 8;
      const float* src = WT + (size_t)(k0 + kb) * 256 + n0 + nq;
      *(float4*)&Bs[kb][nq] = *(const float4*)src;
      *(float4*)&Bs[kb][nq + 4] = *(const float4*)(src + 4);
    }
    __syncthreads();
#pragma unroll
    for (int k = 0; k < 32; ++k) {
      float a0 = As[k][tm * 2 + 0], a1 = As[k][tm * 2 + 1];
      float4 bq = *(const float4*)&Bs[k][tn * 4];
      acc[0][0] += a0 * bq.x; acc[0][1] += a0 * bq.y; acc[0][2] += a0 * bq.z; acc[0][3] += a0 * bq.w;
      acc[1][0] += a1 * bq.x; acc[1][1] += a1 * bq.y; acc[1][2] += a1 * bq.z; acc[1][3] += a1 * bq.w;
    }
  }
#pragma unroll
  for (int i = 0; i < 2; ++i) {
    int r = r0 + tm * 2 + i;
    int j0 = n0 + tn * 4;
    float* dst = C + (size_t)r * 256 + j0;
#pragma unroll
    for (int jj = 0; jj < 4; ++jj) dst[jj] = acc[i][jj] + bias[j0 + jj];
  }
}

// ---------------- mega_a: glimpse logits (o-major) + softmax + weighted sum -> gl ----
__global__ __launch_bounds__(256) void k_mega_a(
    const unsigned char* __restrict__ egt, const unsigned char* __restrict__ egs,
    const float* __restrict__ qp_g, const float* __restrict__ v_g,
    const unsigned char* __restrict__ mask, float* __restrict__ gl)
{
  const int b = blockIdx.x;
  const int tid = threadIdx.x;
  const int lane = tid & 63, wave = tid >> 6;
  __shared__ __align__(16) float qs[256], vs[256];
  __shared__ __align__(16) float up[4][256];
  __shared__ __align__(16) float wbuf[256];
  __shared__ float sred[4];
  __shared__ unsigned char smask[256];

  qs[tid] = qp_g[(size_t)b * 256 + tid];
  vs[tid] = v_g[tid];
  smask[tid] = (tid < NS) ? mask[b * NS + tid] : 1;
  __syncthreads();

  // transposed logits: thread owns s-quad q for o-group g
  const int g = wave, q = lane;
  {
    float a0 = 0.f, a1 = 0.f, a2 = 0.f, a3 = 0.f;
    const unsigned char* base = egt + (size_t)b * 65536 + (size_t)(g * 64) * 256 + 4 * q;
#pragma unroll 8
    for (int k = 0; k < 64; ++k) {
      unsigned int r = *(const unsigned int*)(base + (size_t)k * 256);
      int o = g * 64 + k;
      float qo = qs[o], vo = vs[o];
      f32x2 lo = cvt2_fp8(r), hi = cvt2_fp8(r >> 16);
      a0 = fmaf(vo, fast_tanh(lo.x + qo), a0);
      a1 = fmaf(vo, fast_tanh(lo.y + qo), a1);
      a2 = fmaf(vo, fast_tanh(hi.x + qo), a2);
      a3 = fmaf(vo, fast_tanh(hi.y + qo), a3);
    }
    float4 w4 = { a0, a1, a2, a3 };
    *(float4*)&up[g][4 * q] = w4;
  }
  __syncthreads();
  // combine + mask, then block softmax (one s per thread)
  float uv;
  {
    float u = ((up[0][tid] + up[1][tid]) + up[2][tid]) + up[3][tid];
    uv = (tid < NS && !smask[tid]) ? u : NEG_INF;
  }
  float m = uv;
#pragma unroll
  for (int off = 32; off; off >>= 1) m = fmaxf(m, __shfl_xor(m, off));
  if (lane == 0) sred[wave] = m;
  __syncthreads();
  m = fmaxf(fmaxf(sred[0], sred[1]), fmaxf(sred[2], sred[3]));
  float ex = (uv == NEG_INF) ? 0.0f : fast_expn(uv - m);
  float sm = ex;
#pragma unroll
  for (int off = 32; off; off >>= 1) sm += __shfl_xor(sm, off);
  __syncthreads();
  if (lane == 0) sred[wave] = sm;
  __syncthreads();
  float Z = ((sred[0] + sred[1]) + sred[2]) + sred[3];
  wbuf[tid] = ex * fast_rcp(Z);
  __syncthreads();
  // weighted sum over s (s-major copy): thread owns o=tid
  {
    float acc = 0.f;
    const unsigned char* eb = egs + (size_t)b * (NS * NH) + tid;
#pragma unroll 8
    for (int s = 0; s < NS; ++s)
      acc = fmaf(wbuf[s], cvt2_fp8((unsigned int)eb[(size_t)s * 256]).x, acc);
    gl[(size_t)b * 256 + tid] = acc;
  }
}

// ---------------- mega_b: pointer logits (o-major) + finalize ----------------
__global__ __launch_bounds__(256) void k_mega_b(
    const unsigned char* __restrict__ ept, const float* __restrict__ qp_p,
    const float* __restrict__ v_p, const float* __restrict__ emb,
    unsigned char* __restrict__ mask, float* __restrict__ dec_in,
    float* __restrict__ out_logp, float* __restrict__ out_sels, const int t)
{
  const int b = blockIdx.x;
  const int tid = threadIdx.x;
  const int lane = tid & 63, wave = tid >> 6;
  __shared__ __align__(16) float qs[256], vs[256];
  __shared__ __align__(16) float up[4][256];
  __shared__ float sred[4];
  __shared__ float svals[4];
  __shared__ int sidx[4];
  __shared__ int pick;
  __shared__ unsigned char smask[256];

  qs[tid] = qp_p[(size_t)b * 256 + tid];
  vs[tid] = v_p[tid];
  smask[tid] = (tid < NS) ? mask[b * NS + tid] : 1;
  __syncthreads();

  const int g = wave, q = lane;
  {
    float a0 = 0.f, a1 = 0.f, a2 = 0.f, a3 = 0.f;
    const unsigned char* base = ept + (size_t)b * 65536 + (size_t)(g * 64) * 256 + 4 * q;
#pragma unroll 8
    for (int k = 0; k < 64; ++k) {
      unsigned int r = *(const unsigned int*)(base + (size_t)k * 256);
      int o = g * 64 + k;
      float qo = qs[o], vo = vs[o];
      f32x2 lo = cvt2_fp8(r), hi = cvt2_fp8(r >> 16);
      a0 = fmaf(vo, fast_tanh(lo.x + qo), a0);
      a1 = fmaf(vo, fast_tanh(lo.y + qo), a1);
      a2 = fmaf(vo, fast_tanh(hi.x + qo), a2);
      a3 = fmaf(vo, fast_tanh(hi.y + qo), a3);
    }
    float4 w4 = { a0, a1, a2, a3 };
    *(float4*)&up[g][4 * q] = w4;
  }
  __syncthreads();
  float uv;
  {
    float u = ((up[0][tid] + up[1][tid]) + up[2][tid]) + up[3][tid];
    uv = (tid < NS && !smask[tid]) ? 10.0f * fast_tanh(u) : NEG_INF;
  }
  // log_softmax + argmax + mask + gather
  float m = uv;
#pragma unroll
  for (int off = 32; off; off >>= 1) m = fmaxf(m, __shfl_xor(m, off));
  if (lane == 0) sred[wave] = m;
  __syncthreads();
  m = fmaxf(fmaxf(sred[0], sred[1]), fmaxf(sred[2], sred[3]));
  float ex = (uv == NEG_INF) ? 0.0f : fast_expn(uv - m);
  float sm = ex;
#pragma unroll
  for (int off = 32; off; off >>= 1) sm += __shfl_xor(sm, off);
  __syncthreads();
  if (lane == 0) sred[wave] = sm;
  __syncthreads();
  float Z = ((sred[0] + sred[1]) + sred[2]) + sred[3];
  float lse = fast_log2(Z) * LN2;
  float lp = (uv - m) - lse;
  if (tid < NS) {
    float lp_store = fmaxf(lp, -3.0e38f);  // -inf -> huge finite (harness nan guard)
    out_logp[(size_t)b * (NS * NS) + (size_t)t * NS + tid] = lp_store;
  }
  float av = lp; int ai = tid;
#pragma unroll
  for (int off = 32; off; off >>= 1) {
    float ov = __shfl_xor(av, off);
    int oi = __shfl_xor(ai, off);
    if (ov > av || (ov == av && oi < ai)) { av = ov; ai = oi; }
  }
  if (lane == 0) { svals[wave] = av; sidx[wave] = ai; }
  __syncthreads();
  if (tid == 0) {
    float bv = svals[0]; int bi = sidx[0];
    for (int wv = 1; wv < 4; ++wv) {
      if (svals[wv] > bv || (svals[wv] == bv && sidx[wv] < bi)) { bv = svals[wv]; bi = sidx[wv]; }
    }
    pick = bi;
    out_sels[(size_t)b * NS + t] = (float)bi;
    mask[b * NS + bi] = 1;
  }
  __syncthreads();
  const int s = pick;
  dec_in[(size_t)b * 256 + tid] = emb[(size_t)s * (NB * NH) + (size_t)b * 256 + tid];
}

// ---------------- final h/c copy ----------------
__global__ __launch_bounds__(256) void k_out_hc(
    const float* __restrict__ h, const float* __restrict__ c, float* __restrict__ out)
{
  int i = blockIdx.x * 256 + threadIdx.x;
  if (i < NB * NH) {
    out[OUT_H + i] = h[i];
    out[OUT_C + i] = c[i];
  }
}

// ---------------- host ----------------
extern "C" void kernel_launch(void* const* d_in, const int* in_sizes, int n_in,
                              void* d_out, int out_size, void* d_ws, size_t ws_size,
                              hipStream_t stream)
{
  const float* dec0   = (const float*)d_in[0];
  const float* emb    = (const float*)d_in[1];
  const float* h0     = (const float*)d_in[2];
  const float* c0     = (const float*)d_in[3];
  const float* ctx    = (const float*)d_in[4];
  const float* W_ih   = (const float*)d_in[5];
  const float* W_hh   = (const float*)d_in[6];
  const float* b_ih   = (const float*)d_in[7];
  const float* b_hh   = (const float*)d_in[8];
  const float* Wq_g   = (const float*)d_in[9];
  const float* bq_g   = (const float*)d_in[10];
  const float* Wref_g = (const float*)d_in[11];
  const float* bref_g = (const float*)d_in[12];
  const float* v_g    = (const float*)d_in[13];
  const float* Wq_p   = (const float*)d_in[14];
  const float* bq_p   = (const float*)d_in[15];
  const float* Wref_p = (const float*)d_in[16];
  const float* bref_p = (const float*)d_in[17];
  const float* v_p    = (const float*)d_in[18];

  float* ws = (float*)d_ws;
  float* out = (float*)d_out;
  unsigned char* mask = (unsigned char*)(ws + OFF_MASK);
  unsigned char* egs = (unsigned char*)(ws + OFF_EGS);
  unsigned char* eps = (unsigned char*)(ws + OFF_EPS);
  unsigned char* egt = (unsigned char*)(ws + OFF_EGT);
  unsigned char* ept = (unsigned char*)(ws + OFF_EPT);

  k_init<<<dim3(1024), dim3(256), 0, stream>>>(dec0, h0, c0, W_ih, W_hh, b_ih, b_hh,
                                               Wq_g, Wq_p, Wref_g, Wref_p, ws);
  k_eproj<<<dim3(4, 3200), dim3(256), 0, stream>>>(ctx, ws + OFF_WRTG, bref_g, egs);
  k_eproj<<<dim3(4, 3200), dim3(256), 0, stream>>>(ctx, ws + OFF_WRTP, bref_p, eps);
  k_etr<<<dim3(1024, 4), dim3(256), 0, stream>>>(egs, egt);
  k_etr<<<dim3(1024, 4), dim3(256), 0, stream>>>(eps, ept);

  for (int t = 0; t < NS; ++t) {
    const float* h_in = ws + ((t & 1) ? OFF_H1 : OFF_H0);
    float* h_out      = ws + ((t & 1) ? OFF_H0 : OFF_H1);
    k_gates_lstm<<<dim3(16, 32), dim3(256), 0, stream>>>(
        ws + OFF_DEC, h_in, ws + OFF_WCT, ws + OFF_BSUM, ws + OFF_C, h_out);
    k_mv256<<<dim3(4, 32), dim3(256), 0, stream>>>(
        h_out, ws + OFF_WQTG, bq_g, ws + OFF_QPG);
    k_mega_a<<<dim3(1024), dim3(256), 0, stream>>>(
        egt, egs, ws + OFF_QPG, v_g, mask, ws + OFF_GL);
    k_mv256<<<dim3(4, 32), dim3(256), 0, stream>>>(
        ws + OFF_GL, ws + OFF_WQTP, bq_p, ws + OFF_QPP);
    k_mega_b<<<dim3(1024), dim3(256), 0, stream>>>(
        ept, ws + OFF_QPP, v_p, emb, mask, ws + OFF_DEC, out, out + OUT_SELS, t);
  }
  // final h was written at t=199 (odd) -> OFF_H0
  k_out_hc<<<dim3(1024), dim3(256), 0, stream>>>(ws + OFF_H0, ws + OFF_C, out);
}

// Round 8
// 21086.543 us; speedup vs baseline: 1.0032x; 1.0032x over previous
//
#include <hip/hip_runtime.h>

// Problem sizes
static constexpr int NB = 1024;   // batch
static constexpr int NS = 200;    // seq len
static constexpr int NH = 256;    // hidden == embed
static constexpr int NG4 = 1024;  // 4*H
static constexpr int NK2 = 512;   // E + H

#define NEG_INF (-__builtin_inff())
static constexpr float LOG2E = 1.4426950408889634f;
static constexpr float LN2   = 0.6931471805599453f;

// ---------------- workspace layout (float offsets) ----------------
static constexpr size_t OFF_EGS  = 0;                                   // fp8 [B][200][256]
static constexpr size_t OFF_EPS  = OFF_EGS + (size_t)NB*NS*NH/4;        // fp8 [B][200][256]
static constexpr size_t OFF_WCT  = OFF_EPS + (size_t)NB*NS*NH/4;        // WcatT gate-interleaved [512][1024]
static constexpr size_t OFF_BSUM = OFF_WCT + (size_t)NK2*NG4;           // [1024]
static constexpr size_t OFF_WQTG = OFF_BSUM + 1024;                     // [h][o]
static constexpr size_t OFF_WQTP = OFF_WQTG + (size_t)NH*NH;
static constexpr size_t OFF_WRTG = OFF_WQTP + (size_t)NH*NH;
static constexpr size_t OFF_WRTP = OFF_WRTG + (size_t)NH*NH;
static constexpr size_t OFF_H0   = OFF_WRTP + (size_t)NH*NH;            // h parity
static constexpr size_t OFF_H1   = OFF_H0 + (size_t)NB*NH;
static constexpr size_t OFF_C    = OFF_H1 + (size_t)NB*NH;              // c in-place
static constexpr size_t OFF_DEC  = OFF_C + (size_t)NB*NH;               // dec_in [B][E]
static constexpr size_t OFF_ACT  = OFF_DEC + (size_t)NB*NH;             // int [B][200] active list
static constexpr size_t OFF_POS  = OFF_ACT + (size_t)NB*NS;             // int [B][200] position of s
// ---------------- output layout (float offsets) ----------------
static constexpr size_t OUT_SELS = (size_t)NB*NS*NS;   // log_p first
static constexpr size_t OUT_H    = OUT_SELS + (size_t)NB*NS;
static constexpr size_t OUT_C    = OUT_H + (size_t)NB*NH;

// ---------------- fast math ----------------
typedef float f32x2 __attribute__((ext_vector_type(2)));

__device__ __forceinline__ float fast_exp2(float x) {
  float d; asm("v_exp_f32 %0, %1" : "=v"(d) : "v"(x)); return d;
}
__device__ __forceinline__ float fast_rcp(float x) {
  float d; asm("v_rcp_f32 %0, %1" : "=v"(d) : "v"(x)); return d;
}
__device__ __forceinline__ float fast_log2(float x) {
  float d; asm("v_log_f32 %0, %1" : "=v"(d) : "v"(x)); return d;
}
__device__ __forceinline__ float fast_tanh(float x) {
  float e = fast_exp2(x * (2.0f * LOG2E));
  return fmaf(-2.0f, fast_rcp(e + 1.0f), 1.0f);
}
__device__ __forceinline__ float fast_sigm(float x) {
  float e = fast_exp2(x * (-LOG2E));
  return fast_rcp(1.0f + e);
}
__device__ __forceinline__ float fast_expn(float a) {   // exp(a), a<=0 (or -inf -> 0)
  return fast_exp2(a * LOG2E);
}
__device__ __forceinline__ f32x2 cvt2_fp8(unsigned int u) {
  f32x2 d; asm("v_cvt_pk_f32_fp8 %0, %1" : "=v"(d) : "v"(u)); return d;
}
__device__ __forceinline__ unsigned int f32_to_e4m3(float x) {
  x = fminf(fmaxf(x, -448.0f), 448.0f);
  unsigned int u = __float_as_uint(x);
  unsigned int s = (u >> 24) & 0x80u;
  unsigned int au = u & 0x7fffffffu;
  if (au < 0x3c800000u) return s;
  unsigned int r = au + 0x7ffffu + ((au >> 20) & 1u);
  unsigned int expf8 = (r >> 23) - 120u;
  unsigned int man = (r >> 20) & 7u;
  return s | (expf8 << 3) | man;
}

// ---------------- init ----------------
__global__ __launch_bounds__(256) void k_init(
    const float* __restrict__ dec0, const float* __restrict__ h0, const float* __restrict__ c0,
    const float* __restrict__ W_ih, const float* __restrict__ W_hh,
    const float* __restrict__ b_ih, const float* __restrict__ b_hh,
    const float* __restrict__ Wq_g, const float* __restrict__ Wq_p,
    const float* __restrict__ Wref_g, const float* __restrict__ Wref_p,
    float* __restrict__ ws)
{
  const int i0 = blockIdx.x * 256 + threadIdx.x;
  const int stride = gridDim.x * 256;
  float* WcatT = ws + OFF_WCT;
  float* BS   = ws + OFF_BSUM;
  float* WqTg = ws + OFF_WQTG;
  float* WqTp = ws + OFF_WQTP;
  float* WrTg = ws + OFF_WRTG;
  float* WrTp = ws + OFF_WRTP;
  for (int t = i0; t < NK2 * NG4; t += stride) {
    int k = t >> 10, j = t & 1023;
    int hcol = j >> 2, g = j & 3;
    int row = g * 256 + hcol;
    WcatT[t] = (k < NH) ? W_ih[row * NH + k] : W_hh[row * NH + (k - NH)];
  }
  for (int t = i0; t < 1024; t += stride) {
    int hcol = t >> 2, g = t & 3;
    BS[t] = b_ih[g * 256 + hcol] + b_hh[g * 256 + hcol];
  }
  for (int t = i0; t < NH * NH; t += stride) {
    int h = t >> 8, o = t & 255;
    WqTg[t] = Wq_g[o * NH + h];
    WqTp[t] = Wq_p[o * NH + h];
    WrTg[t] = Wref_g[o * NH + h];
    WrTp[t] = Wref_p[o * NH + h];
  }
  float* hbuf = ws + OFF_H0;
  float* cbuf = ws + OFF_C;
  float* dbuf = ws + OFF_DEC;
  for (int t = i0; t < NB * NH; t += stride) {
    hbuf[t] = h0[t]; cbuf[t] = c0[t]; dbuf[t] = dec0[t];
  }
  int* act = (int*)(ws + OFF_ACT);
  int* pos = (int*)(ws + OFF_POS);
  for (int t = i0; t < NB * NS; t += stride) {
    int s = t % NS;
    act[t] = s; pos[t] = s;
  }
}

// ---------------- e projection GEMM -> fp8 [B][S][O] ----------------
__global__ __launch_bounds__(256) void k_eproj(
    const float* __restrict__ A,    // context flat [S*B][256]
    const float* __restrict__ WT,   // [256][256]
    const float* __restrict__ bias,
    unsigned char* __restrict__ e)  // [B][200][256] fp8
{
  __shared__ float As[32][68];
  __shared__ float Bs[32][68];
  const int r0 = blockIdx.y * 64;
  const int n0 = blockIdx.x * 64;
  const int tid = threadIdx.x;
  const int tm = tid & 15, tn = tid >> 4;
  float acc[4][4] = {};
  for (int k0 = 0; k0 < 256; k0 += 32) {
    __syncthreads();
    {
      const int m = tid >> 2;
      const int kq = (tid & 3) * 8;
      const float* src = A + (size_t)(r0 + m) * 256 + k0 + kq;
      float4 v0 = *(const float4*)src;
      float4 v1 = *(const float4*)(src + 4);
      As[kq + 0][m] = v0.x; As[kq + 1][m] = v0.y; As[kq + 2][m] = v0.z; As[kq + 3][m] = v0.w;
      As[kq + 4][m] = v1.x; As[kq + 5][m] = v1.y; As[kq + 6][m] = v1.z; As[kq + 7][m] = v1.w;
    }
    {
      const int kb = tid >> 3;
      const int nq = (tid & 7) * 8;
      const float* src = WT + (size_t)(k0 + kb) * 256 + n0 + nq;
      *(float4*)&Bs[kb][nq] = *(const float4*)src;
      *(float4*)&Bs[kb][nq + 4] = *(const float4*)(src + 4);
    }
    __syncthreads();
#pragma unroll
    for (int k = 0; k < 32; ++k) {
      float4 a = *(const float4*)&As[k][tm * 4];
      float4 bq = *(const float4*)&Bs[k][tn * 4];
      float av[4] = {a.x, a.y, a.z, a.w};
      float bv[4] = {bq.x, bq.y, bq.z, bq.w};
#pragma unroll
      for (int i = 0; i < 4; ++i)
#pragma unroll
        for (int j = 0; j < 4; ++j) acc[i][j] += av[i] * bv[j];
    }
  }
  float4 bvv = *(const float4*)(bias + n0 + tn * 4);
  float bb[4] = {bvv.x, bvv.y, bvv.z, bvv.w};
#pragma unroll
  for (int i = 0; i < 4; ++i) {
    int R = r0 + tm * 4 + i;
    int b = R & 1023, s = R >> 10;
    unsigned int pk = f32_to_e4m3(acc[i][0] + bb[0])
                    | (f32_to_e4m3(acc[i][1] + bb[1]) << 8)
                    | (f32_to_e4m3(acc[i][2] + bb[2]) << 16)
                    | (f32_to_e4m3(acc[i][3] + bb[3]) << 24);
    *(unsigned int*)(e + (size_t)b * (NS * NH) + (size_t)s * NH + n0 + tn * 4) = pk;
  }
}

// ---------------- gates GEMM + fused LSTM activation ----------------
__global__ __launch_bounds__(256) void k_gates_lstm(
    const float* __restrict__ dec_in, const float* __restrict__ h_in,
    const float* __restrict__ WcatT, const float* __restrict__ BS,
    float* __restrict__ c, float* __restrict__ h_out)
{
  __shared__ float As[32][34];
  __shared__ float Bs[32][68];
  const int r0 = blockIdx.y * 32;
  const int n0 = blockIdx.x * 64;
  const int tid = threadIdx.x;
  const int tm = tid & 15, tn = tid >> 4;
  float acc[2][4] = {};
  for (int k0 = 0; k0 < 512; k0 += 32) {
    __syncthreads();
    {
      const int m = tid >> 3;
      const int kq = (tid & 7) * 4;
      const int kk = k0 + kq;
      const float* src = (kk < 256) ? (dec_in + (size_t)(r0 + m) * 256 + kk)
                                    : (h_in + (size_t)(r0 + m) * 256 + (kk - 256));
      float4 v = *(const float4*)src;
      As[kq + 0][m] = v.x; As[kq + 1][m] = v.y; As[kq + 2][m] = v.z; As[kq + 3][m] = v.w;
    }
    {
      const int kb = tid >> 3;
      const int nq = (tid & 7) * 8;
      const float* src = WcatT + (size_t)(k0 + kb) * 1024 + n0 + nq;
      *(float4*)&Bs[kb][nq] = *(const float4*)src;
      *(float4*)&Bs[kb][nq + 4] = *(const float4*)(src + 4);
    }
    __syncthreads();
#pragma unroll
    for (int k = 0; k < 32; ++k) {
      float a0 = As[k][tm * 2 + 0], a1 = As[k][tm * 2 + 1];
      float4 bq = *(const float4*)&Bs[k][tn * 4];
      acc[0][0] += a0 * bq.x; acc[0][1] += a0 * bq.y; acc[0][2] += a0 * bq.z; acc[0][3] += a0 * bq.w;
      acc[1][0] += a1 * bq.x; acc[1][1] += a1 * bq.y; acc[1][2] += a1 * bq.z; acc[1][3] += a1 * bq.w;
    }
  }
  const int j0 = n0 + tn * 4;
  const int hc = (j0 >> 2);
  float b0 = BS[j0], b1 = BS[j0 + 1], b2 = BS[j0 + 2], b3 = BS[j0 + 3];
#pragma unroll
  for (int i = 0; i < 2; ++i) {
    int r = r0 + tm * 2 + i;
    float gi = acc[i][0] + b0;
    float gf = acc[i][1] + b1;
    float gg = acc[i][2] + b2;
    float go = acc[i][3] + b3;
    float cprev = c[(size_t)r * 256 + hc];
    float cn = fast_sigm(gf) * cprev + fast_sigm(gi) * fast_tanh(gg);
    c[(size_t)r * 256 + hc] = cn;
    h_out[(size_t)r * 256 + hc] = fast_sigm(go) * fast_tanh(cn);
  }
}

// ---------------- mega: qp_g, glimpse(active), softmax, wsum(active), qp_p,
//                  pointer(active), finalize — one block per b ----------------
__global__ __launch_bounds__(256) void k_mega(
    const unsigned char* __restrict__ egs, const unsigned char* __restrict__ eps,
    const float* __restrict__ h, const float* __restrict__ WqTg,
    const float* __restrict__ bq_g, const float* __restrict__ v_g,
    const float* __restrict__ v_p, const float* __restrict__ WqTp,
    const float* __restrict__ bq_p, const float* __restrict__ emb,
    int* __restrict__ act_g, int* __restrict__ pos_g,
    float* __restrict__ dec_in, float* __restrict__ out_logp,
    float* __restrict__ out_sels, const int t)
{
  const int b = blockIdx.x;
  const int tid = threadIdx.x;
  const int lane = tid & 63, wave = tid >> 6;
  const int nact = NS - t;
  __shared__ __align__(16) float hs[256];
  __shared__ __align__(16) float qpg_s[256];
  __shared__ __align__(16) float u_s[256];
  __shared__ __align__(16) float wbuf[256];
  __shared__ __align__(16) float gl_s[256];
  __shared__ __align__(16) float qpp_s[256];
  __shared__ int act_s[NS];
  __shared__ float sred[4];
  __shared__ float svals[4];
  __shared__ int sidx[4];
  __shared__ int pick;

  hs[tid] = h[(size_t)b * 256 + tid];
  if (tid < NS) act_s[tid] = act_g[(size_t)b * NS + tid];
  u_s[tid] = NEG_INF;
  __syncthreads();

  // ---- P0: qp_g = h[b] . WqTg + bq_g
  {
    float a = 0.0f;
#pragma unroll 16
    for (int k = 0; k < 256; ++k) a = fmaf(hs[k], WqTg[(size_t)k * 256 + tid], a);
    qpg_s[tid] = a + bq_g[tid];
  }
  __syncthreads();

  const unsigned char* egb = egs + (size_t)b * (NS * NH);
  const unsigned char* epb = eps + (size_t)b * (NS * NH);

  // ---- P1: glimpse logits over ACTIVE rows (wave-per-row, 2-row interleave)
  {
    float4 qv; qv.x = qpg_s[lane*4]; qv.y = qpg_s[lane*4+1]; qv.z = qpg_s[lane*4+2]; qv.w = qpg_s[lane*4+3];
    float4 vv = *(const float4*)(v_g + lane * 4);
    int j = wave;
    for (; j + 4 < nact; j += 8) {
      int s0 = act_s[j], s1 = act_s[j + 4];
      unsigned int r0 = *(const unsigned int*)(egb + (size_t)s0 * NH + 4 * lane);
      unsigned int r1 = *(const unsigned int*)(egb + (size_t)s1 * NH + 4 * lane);
      f32x2 a01 = cvt2_fp8(r0), a23 = cvt2_fp8(r0 >> 16);
      f32x2 b01 = cvt2_fp8(r1), b23 = cvt2_fp8(r1 >> 16);
      float t0 = vv.x * fast_tanh(a01.x + qv.x);
      t0 = fmaf(vv.y, fast_tanh(a01.y + qv.y), t0);
      t0 = fmaf(vv.z, fast_tanh(a23.x + qv.z), t0);
      t0 = fmaf(vv.w, fast_tanh(a23.y + qv.w), t0);
      float t1 = vv.x * fast_tanh(b01.x + qv.x);
      t1 = fmaf(vv.y, fast_tanh(b01.y + qv.y), t1);
      t1 = fmaf(vv.z, fast_tanh(b23.x + qv.z), t1);
      t1 = fmaf(vv.w, fast_tanh(b23.y + qv.w), t1);
#pragma unroll
      for (int off = 32; off; off >>= 1) t0 += __shfl_xor(t0, off);
#pragma unroll
      for (int off = 32; off; off >>= 1) t1 += __shfl_xor(t1, off);
      if (lane == 0) { u_s[s0] = t0; u_s[s1] = t1; }
    }
    if (j < nact) {
      int s0 = act_s[j];
      unsigned int r0 = *(const unsigned int*)(egb + (size_t)s0 * NH + 4 * lane);
      f32x2 a01 = cvt2_fp8(r0), a23 = cvt2_fp8(r0 >> 16);
      float t0 = vv.x * fast_tanh(a01.x + qv.x);
      t0 = fmaf(vv.y, fast_tanh(a01.y + qv.y), t0);
      t0 = fmaf(vv.z, fast_tanh(a23.x + qv.z), t0);
      t0 = fmaf(vv.w, fast_tanh(a23.y + qv.w), t0);
#pragma unroll
      for (int off = 32; off; off >>= 1) t0 += __shfl_xor(t0, off);
      if (lane == 0) u_s[s0] = t0;
    }
  }
  __syncthreads();

  // ---- P2: softmax -> wbuf (masked entries exact 0)
  {
    float uv = (tid < NS) ? u_s[tid] : NEG_INF;
    float m = uv;
#pragma unroll
    for (int off = 32; off; off >>= 1) m = fmaxf(m, __shfl_xor(m, off));
    if (lane == 0) sred[wave] = m;
    __syncthreads();
    m = fmaxf(fmaxf(sred[0], sred[1]), fmaxf(sred[2], sred[3]));
    float ex = (uv == NEG_INF) ? 0.0f : fast_expn(uv - m);
    float sm = ex;
#pragma unroll
    for (int off = 32; off; off >>= 1) sm += __shfl_xor(sm, off);
    __syncthreads();
    if (lane == 0) sred[wave] = sm;
    __syncthreads();
    float Z = ((sred[0] + sred[1]) + sred[2]) + sred[3];
    wbuf[tid] = ex * fast_rcp(Z);
  }
  __syncthreads();

  // ---- P3: gl[o] = sum over ACTIVE s of w[s]*e_g[s][o]  (thread = o)
  {
    float acc = 0.f;
    const unsigned char* eb = egb + tid;
#pragma unroll 8
    for (int j = 0; j < nact; ++j) {
      int s = act_s[j];
      acc = fmaf(wbuf[s], cvt2_fp8((unsigned int)eb[(size_t)s * 256]).x, acc);
    }
    gl_s[tid] = acc;
  }
  __syncthreads();

  // ---- P4: qp_p = gl . WqTp + bq_p ; reset u_s for pointer pass
  {
    float a2 = bq_p[tid];
#pragma unroll 16
    for (int o = 0; o < 256; ++o) a2 = fmaf(WqTp[(size_t)o * 256 + tid], gl_s[o], a2);
    qpp_s[tid] = a2;
  }
  u_s[tid] = NEG_INF;
  __syncthreads();

  // ---- P5: pointer logits over ACTIVE rows
  {
    float4 qv; qv.x = qpp_s[lane*4]; qv.y = qpp_s[lane*4+1]; qv.z = qpp_s[lane*4+2]; qv.w = qpp_s[lane*4+3];
    float4 vv = *(const float4*)(v_p + lane * 4);
    int j = wave;
    for (; j + 4 < nact; j += 8) {
      int s0 = act_s[j], s1 = act_s[j + 4];
      unsigned int r0 = *(const unsigned int*)(epb + (size_t)s0 * NH + 4 * lane);
      unsigned int r1 = *(const unsigned int*)(epb + (size_t)s1 * NH + 4 * lane);
      f32x2 a01 = cvt2_fp8(r0), a23 = cvt2_fp8(r0 >> 16);
      f32x2 b01 = cvt2_fp8(r1), b23 = cvt2_fp8(r1 >> 16);
      float t0 = vv.x * fast_tanh(a01.x + qv.x);
      t0 = fmaf(vv.y, fast_tanh(a01.y + qv.y), t0);
      t0 = fmaf(vv.z, fast_tanh(a23.x + qv.z), t0);
      t0 = fmaf(vv.w, fast_tanh(a23.y + qv.w), t0);
      float t1 = vv.x * fast_tanh(b01.x + qv.x);
      t1 = fmaf(vv.y, fast_tanh(b01.y + qv.y), t1);
      t1 = fmaf(vv.z, fast_tanh(b23.x + qv.z), t1);
      t1 = fmaf(vv.w, fast_tanh(b23.y + qv.w), t1);
#pragma unroll
      for (int off = 32; off; off >>= 1) t0 += __shfl_xor(t0, off);
#pragma unroll
      for (int off = 32; off; off >>= 1) t1 += __shfl_xor(t1, off);
      if (lane == 0) { u_s[s0] = 10.0f * fast_tanh(t0); u_s[s1] = 10.0f * fast_tanh(t1); }
    }
    if (j < nact) {
      int s0 = act_s[j];
      unsigned int r0 = *(const unsigned int*)(epb + (size_t)s0 * NH + 4 * lane);
      f32x2 a01 = cvt2_fp8(r0), a23 = cvt2_fp8(r0 >> 16);
      float t0 = vv.x * fast_tanh(a01.x + qv.x);
      t0 = fmaf(vv.y, fast_tanh(a01.y + qv.y), t0);
      t0 = fmaf(vv.z, fast_tanh(a23.x + qv.z), t0);
      t0 = fmaf(vv.w, fast_tanh(a23.y + qv.w), t0);
#pragma unroll
      for (int off = 32; off; off >>= 1) t0 += __shfl_xor(t0, off);
      if (lane == 0) u_s[s0] = 10.0f * fast_tanh(t0);
    }
  }
  __syncthreads();

  // ---- P6: log_softmax, store, argmax (tie->lowest), active-list update, gather
  {
    float uv = (tid < NS) ? u_s[tid] : NEG_INF;
    float m = uv;
#pragma unroll
    for (int off = 32; off; off >>= 1) m = fmaxf(m, __shfl_xor(m, off));
    if (lane == 0) sred[wave] = m;
    __syncthreads();
    m = fmaxf(fmaxf(sred[0], sred[1]), fmaxf(sred[2], sred[3]));
    float ex = (uv == NEG_INF) ? 0.0f : fast_expn(uv - m);
    float sm = ex;
#pragma unroll
    for (int off = 32; off; off >>= 1) sm += __shfl_xor(sm, off);
    __syncthreads();
    if (lane == 0) sred[wave] = sm;
    __syncthreads();
    float Z = ((sred[0] + sred[1]) + sred[2]) + sred[3];
    float lse = fast_log2(Z) * LN2;
    float lp = (uv - m) - lse;
    if (tid < NS) {
      float lp_store = fmaxf(lp, -3.0e38f);  // -inf -> huge finite (harness nan guard)
      out_logp[(size_t)b * (NS * NS) + (size_t)t * NS + tid] = lp_store;
    }
    float av = lp; int ai = tid;
#pragma unroll
    for (int off = 32; off; off >>= 1) {
      float ov = __shfl_xor(av, off);
      int oi = __shfl_xor(ai, off);
      if (ov > av || (ov == av && oi < ai)) { av = ov; ai = oi; }
    }
    if (lane == 0) { svals[wave] = av; sidx[wave] = ai; }
    __syncthreads();
    if (tid == 0) {
      float bv = svals[0]; int bi = sidx[0];
      for (int wv = 1; wv < 4; ++wv) {
        if (svals[wv] > bv || (svals[wv] == bv && sidx[wv] < bi)) { bv = svals[wv]; bi = sidx[wv]; }
      }
      pick = bi;
      out_sels[(size_t)b * NS + t] = (float)bi;
      int j = pos_g[(size_t)b * NS + bi];
      int last = act_g[(size_t)b * NS + (nact - 1)];
      act_g[(size_t)b * NS + j] = last;
      pos_g[(size_t)b * NS + last] = j;
    }
    __syncthreads();
    const int s = pick;
    dec_in[(size_t)b * 256 + tid] = emb[(size_t)s * (NB * NH) + (size_t)b * 256 + tid];
  }
}

// ---------------- final h/c copy ----------------
__global__ __launch_bounds__(256) void k_out_hc(
    const float* __restrict__ h, const float* __restrict__ c, float* __restrict__ out)
{
  int i = blockIdx.x * 256 + threadIdx.x;
  if (i < NB * NH) {
    out[OUT_H + i] = h[i];
    out[OUT_C + i] = c[i];
  }
}

// ---------------- host ----------------
extern "C" void kernel_launch(void* const* d_in, const int* in_sizes, int n_in,
                              void* d_out, int out_size, void* d_ws, size_t ws_size,
                              hipStream_t stream)
{
  const float* dec0   = (const float*)d_in[0];
  const float* emb    = (const float*)d_in[1];
  const float* h0     = (const float*)d_in[2];
  const float* c0     = (const float*)d_in[3];
  const float* ctx    = (const float*)d_in[4];
  const float* W_ih   = (const float*)d_in[5];
  const float* W_hh   = (const float*)d_in[6];
  const float* b_ih   = (const float*)d_in[7];
  const float* b_hh   = (const float*)d_in[8];
  const float* Wq_g   = (const float*)d_in[9];
  const float* bq_g   = (const float*)d_in[10];
  const float* Wref_g = (const float*)d_in[11];
  const float* bref_g = (const float*)d_in[12];
  const float* v_g    = (const float*)d_in[13];
  const float* Wq_p   = (const float*)d_in[14];
  const float* bq_p   = (const float*)d_in[15];
  const float* Wref_p = (const float*)d_in[16];
  const float* bref_p = (const float*)d_in[17];
  const float* v_p    = (const float*)d_in[18];

  float* ws = (float*)d_ws;
  float* out = (float*)d_out;
  unsigned char* egs = (unsigned char*)(ws + OFF_EGS);
  unsigned char* eps = (unsigned char*)(ws + OFF_EPS);
  int* act = (int*)(ws + OFF_ACT);
  int* pos = (int*)(ws + OFF_POS);

  k_init<<<dim3(1024), dim3(256), 0, stream>>>(dec0, h0, c0, W_ih, W_hh, b_ih, b_hh,
                                               Wq_g, Wq_p, Wref_g, Wref_p, ws);
  k_eproj<<<dim3(4, 3200), dim3(256), 0, stream>>>(ctx, ws + OFF_WRTG, bref_g, egs);
  k_eproj<<<dim3(4, 3200), dim3(256), 0, stream>>>(ctx, ws + OFF_WRTP, bref_p, eps);

  for (int t = 0; t < NS; ++t) {
    const float* h_in = ws + ((t & 1) ? OFF_H1 : OFF_H0);
    float* h_out      = ws + ((t & 1) ? OFF_H0 : OFF_H1);
    k_gates_lstm<<<dim3(16, 32), dim3(256), 0, stream>>>(
        ws + OFF_DEC, h_in, ws + OFF_WCT, ws + OFF_BSUM, ws + OFF_C, h_out);
    k_mega<<<dim3(1024), dim3(256), 0, stream>>>(
        egs, eps, h_out, ws + OFF_WQTG, bq_g, v_g, v_p, ws + OFF_WQTP, bq_p,
        emb, act, pos, ws + OFF_DEC, out, out + OUT_SELS, t);
  }
  // t=199 odd: h_out = OFF_H0
  k_out_hc<<<dim3(1024), dim3(256), 0, stream>>>(ws + OFF_H0, ws + OFF_C, out);
}